// Round 17
// baseline (187.327 us; speedup 1.0000x reference)
//
#include <hip/hip_runtime.h>
#include <stdint.h>

#define B_SZ 4096
#define D_SZ 512
#define SHIFT 64.0f

typedef __attribute__((ext_vector_type(4))) float floatx4;
typedef __attribute__((ext_vector_type(2))) long lng2;
typedef unsigned char u8;
typedef unsigned int u32;

#define GLD_LDS16(gp, sp)                                                              \
    __builtin_amdgcn_global_load_lds(                                                  \
        (const __attribute__((address_space(1))) void*)(gp),                           \
        (__attribute__((address_space(3))) void*)(sp), 16, 0, 0)

// ---- K1: fp32->fp8(e4m3) convert (K-interleaved layout) + per-row time,
//      fused: histogram (block 0), accumulator zeroing, entailment partials.
//      K-perm: within each 64B K-window, 8B group (h,c) -> slot c*2+h; applied
//      to BOTH operands => Grammian unchanged. ----
__global__ __launch_bounds__(256) void prep_kernel(
    const float* __restrict__ img, const float* __restrict__ dna,
    const float* __restrict__ txt, const float* __restrict__ curv_p,
    const int* __restrict__ labels, int* __restrict__ hist,
    u8* __restrict__ f8, float* __restrict__ times,
    float* __restrict__ zero_f, float* __restrict__ ent_partial) {
    __shared__ int lhist[512];
    __shared__ float red[4];
    int t = threadIdx.x;
    int gid = blockIdx.x * 256 + t;
    if (gid < 49155) zero_f[gid] = 0.0f;    // rsum/csum + ce_acc/ent_acc/done

    if (blockIdx.x == 0) {                  // label histogram, single block
        lhist[t] = 0; lhist[t + 256] = 0;
        __syncthreads();
        for (int n = t; n < B_SZ; n += 256) atomicAdd(&lhist[labels[n]], 1);
        __syncthreads();
        hist[t] = lhist[t]; hist[t + 256] = lhist[t + 256];
    }

    int wave = gid >> 6;  // 0..12287
    int lane = t & 63;
    const float* src = (wave < B_SZ) ? img : (wave < 2 * B_SZ) ? dna : txt;
    int row = wave & (B_SZ - 1);
    const float* p = src + row * D_SZ + lane * 8;
    float4 v0 = *(const float4*)(p);
    float4 v1 = *(const float4*)(p + 4);
    float ss = v0.x*v0.x + v0.y*v0.y + v0.z*v0.z + v0.w*v0.w
             + v1.x*v1.x + v1.y*v1.y + v1.z*v1.z + v1.w*v1.w;
    u32 w0 = __builtin_amdgcn_cvt_pk_fp8_f32(v0.x, v0.y, 0, false);
    w0 = __builtin_amdgcn_cvt_pk_fp8_f32(v0.z, v0.w, w0, true);
    u32 w1 = __builtin_amdgcn_cvt_pk_fp8_f32(v1.x, v1.y, 0, false);
    w1 = __builtin_amdgcn_cvt_pk_fp8_f32(v1.z, v1.w, w1, true);
    uint2 pk; pk.x = w0; pk.y = w1;
    // lane = 8B group: window lane>>3, half (lane>>2)&1, chunk lane&3
    int gperm = (lane & 56) | ((lane & 3) << 1) | ((lane >> 2) & 1);
    *(uint2*)(f8 + (size_t)wave * D_SZ + gperm * 8) = pk;

    bool isdna = (wave >= B_SZ) && (wave < 2 * B_SZ);
    float dot = 0.0f, ssy = 0.0f;
    if (isdna) {                            // matching image row for entailment
        const float* y = img + row * D_SZ + lane * 8;
        float4 y0 = *(const float4*)y, y1 = *(const float4*)(y + 4);
        dot = v0.x*y0.x + v0.y*y0.y + v0.z*y0.z + v0.w*y0.w
            + v1.x*y1.x + v1.y*y1.y + v1.z*y1.z + v1.w*y1.w;
        ssy = y0.x*y0.x + y0.y*y0.y + y0.z*y0.z + y0.w*y0.w
            + y1.x*y1.x + y1.y*y1.y + y1.z*y1.z + y1.w*y1.w;
    }
    #pragma unroll
    for (int m = 1; m < 64; m <<= 1) {
        ss += __shfl_xor(ss, m);
        if (isdna) { dot += __shfl_xor(dot, m); ssy += __shfl_xor(ssy, m); }
    }
    float curv = curv_p[0];
    float ep = 0.0f;
    if (lane == 0) {
        float xt = sqrtf(1.0f / curv + ss);
        times[wave] = xt;
        if (isdna) {
            float yt = sqrtf(1.0f / curv + ssy);
            float nx = sqrtf(ss);
            float c = curv * (dot - xt * yt);                      // <= -1
            float numer = yt + c * xt;
            float denom = nx * sqrtf(fmaxf(c * c - 1.0f, 0.0f));
            float ai = numer / (denom + 1e-8f);
            ai = fminf(fmaxf(ai, -1.0f + 1e-8f), 1.0f - 1e-8f);
            float ang = acosf(ai);
            float as_in = 0.2f / (nx * sqrtf(curv) + 1e-6f);       // 2*min_radius
            as_in = fminf(fmaxf(as_in, -1.0f + 1e-6f), 1.0f - 1e-6f);
            float ap = asinf(as_in);
            ep = fmaxf(ang - ap, 0.0f);
        }
    }
    if (blockIdx.x >= 1024 && blockIdx.x < 2048) {   // pure-dna blocks
        if (lane == 0) red[t >> 6] = ep;
        __syncthreads();
        if (t == 0) ent_partial[blockIdx.x - 1024] = red[0] + red[1] + red[2] + red[3];
    }
}

// ---- K2: batched fp8 MFMA GEMM (A·B^T), 256x256 tile, 1024 threads = 16
//      waves, 64x64 patch/wave (R14's exact per-wave body, ~92 regs).
//      K-interleaved fp8 => b128 frag reads, bijective swizzle
//      slot = r*4+(q^((r>>1)&3)) (0 conflicts R14/R16).
//      SPILL-TRAP FIX (R9-R12 + R14 lessons): allocator budgets VGPRs from
//      LDS-derived residency. sB carries a 24 KB in-object pad (R14-verified
//      pads inside used arrays survive; R12's separate array was stripped):
//      LDS = 88 KB -> 1 block/CU -> 16 waves/CU -> 4 waves/EU -> 128-VGPR
//      budget -> 92-reg body fits, no spill. Staging traffic 192 MB (vs 288),
//      blocks 768 (vs 1536) -> half the prologue/epilogue convoys. ----
__global__ __launch_bounds__(1024) void gemm_epi_kernel(
    const u8* __restrict__ f8, const float* __restrict__ times,
    const int* __restrict__ labels,
    const float* __restrict__ ls_p, const float* __restrict__ curv_p,
    float* __restrict__ rsum_e, float* __restrict__ rsum_t,
    float* __restrict__ csum_e, float* __restrict__ csum_t) {
    __shared__ u8 sA[2][16384];   // 32 KB: 256 rows x 64 B per buffer
    __shared__ u8 sB[2][28672];   // 56 KB; per buf only [0,16384) used,
                                  // [16384,28672) = occupancy-shaper pad

    int z = blockIdx.z;                   // 0:(img,dna) 1:(img,txt) 2:(dna,txt)
    int pa = (z == 2) ? 1 : 0;
    int pb = (z == 0) ? 1 : 2;
    const u8* A  = f8 + (size_t)pa * (B_SZ * D_SZ);
    const u8* Bm = f8 + (size_t)pb * (B_SZ * D_SZ);

    int t = threadIdx.x;
    int rowBlk = blockIdx.y * 256;
    int colBlk = blockIdx.x * 256;
    int wave = t >> 6, lane = t & 63;
    int rq = wave >> 2;                   // row 64-group (0..3)
    int ch = wave & 3;                    // col 64-group (0..3)

    // staging: wave w stages A rows [w*16,+16) and B rows [w*16,+16), 1 GLD
    // each (rows are 64 B). Lane: row lane>>2, source 16B chunk
    // (lane&3)^((lane>>3)&3) => stored slot r*4 + (c^((r>>1)&3)).
    int lrow = lane >> 2;
    int lch  = (lane & 3) ^ ((lane >> 3) & 3);
    const u8* gA = A  + (size_t)(rowBlk + wave * 16 + lrow) * D_SZ + lch * 16;
    const u8* gB = Bm + (size_t)(colBlk + wave * 16 + lrow) * D_SZ + lch * 16;

    int q = lane >> 4, s = lane & 15;

    floatx4 acc[4][4];
    #pragma unroll
    for (int ii = 0; ii < 4; ++ii)
        #pragma unroll
        for (int j = 0; j < 4; ++j) acc[ii][j] = (floatx4){0.f, 0.f, 0.f, 0.f};

    {   // prologue: stage super-iter 0 (K-bytes [0,64)) into buffer 0
        GLD_LDS16(gA, &sA[0][wave * 1024]);
        GLD_LDS16(gB, &sB[0][wave * 1024]);
    }

    for (int si = 0; si < D_SZ / 64; ++si) {
        int cur = si & 1;
        __syncthreads();   // buf[cur] landed; prior frag reads done
        if (si < D_SZ / 64 - 1) {
            int ko = (si + 1) * 64;
            int nxt = cur ^ 1;
            GLD_LDS16(gA + ko, &sA[nxt][wave * 1024]);
            GLD_LDS16(gB + ko, &sB[nxt][wave * 1024]);
        }
        lng2 afp[4], bfp[4];
        #pragma unroll
        for (int ii = 0; ii < 4; ++ii) {
            int r = rq * 64 + ii * 16 + s;
            afp[ii] = *(const lng2*)&sA[cur][r * 64 + ((q ^ ((r >> 1) & 3)) << 4)];
        }
        #pragma unroll
        for (int j = 0; j < 4; ++j) {
            int r = ch * 64 + j * 16 + s;
            bfp[j] = *(const lng2*)&sB[cur][r * 64 + ((q ^ ((r >> 1) & 3)) << 4)];
        }
        #pragma unroll
        for (int ii = 0; ii < 4; ++ii)
            #pragma unroll
            for (int j = 0; j < 4; ++j) {
                acc[ii][j] = __builtin_amdgcn_mfma_f32_16x16x32_fp8_fp8(
                    afp[ii].x, bfp[j].x, acc[ii][j], 0, 0, 0);
                acc[ii][j] = __builtin_amdgcn_mfma_f32_16x16x32_fp8_fp8(
                    afp[ii].y, bfp[j].y, acc[ii][j], 0, 0, 0);
            }
    }

    // ---- slim fused epilogue (verified R7-R16) ----
    float ls = ls_p[0];
    float curv = curv_p[0];
    float rsc = rsqrtf(curv);
    float c2 = -ls * rsc;
    float c1 = c2 * 0.69314718f;
    float sh2p = SHIFT * 1.44269504f + c2;
    const float* tA = times + pa * B_SZ;
    const float* tB = times + pb * B_SZ;

    int rowbase = rowBlk + rq * 64;
    int colbase = colBlk + ch * 64;

    float tb[4]; int lb[4]; int mcol[4];
    #pragma unroll
    for (int j = 0; j < 4; ++j) {
        mcol[j] = colbase + j * 16 + s;
        tb[j] = tB[mcol[j]];
        lb[j] = labels[mcol[j]];
    }
    float colE[4] = {0.f, 0.f, 0.f, 0.f}, colT[4] = {0.f, 0.f, 0.f, 0.f};

    float* rsE = rsum_e + z * B_SZ;
    float* rsT = rsum_t + z * B_SZ;
    float* csE = csum_e + z * B_SZ;
    float* csT = csum_t + z * B_SZ;

    #pragma unroll
    for (int ii = 0; ii < 4; ++ii) {
        int nb = rowbase + ii * 16 + q * 4;   // this lane's 4 C rows
        float cta[4]; int la[4];
        #pragma unroll
        for (int r = 0; r < 4; ++r) { cta[r] = curv * tA[nb + r]; la[r] = labels[nb + r]; }
        float re[4] = {0.f, 0.f, 0.f, 0.f}, rt[4] = {0.f, 0.f, 0.f, 0.f};
        #pragma unroll
        for (int j = 0; j < 4; ++j) {
            floatx4 a = acc[ii][j];
            #pragma unroll
            for (int r = 0; r < 4; ++r) {
                float zc = fmaf(-curv, a[r], cta[r] * tb[j]);
                zc = fmaxf(zc, 1.0f + 1e-8f);
                float lz = __log2f(zc);
                float e = __builtin_amdgcn_exp2f(fmaf(c2, lz, sh2p));
                float tl = (la[r] == lb[j]) ? fmaf(c1, lz, c1) : 0.0f;
                re[r] += e; rt[r] += tl;
                colE[j] += e; colT[j] += tl;
            }
        }
        #pragma unroll
        for (int r = 0; r < 4; ++r) {
            #pragma unroll
            for (int m = 1; m <= 8; m <<= 1) {
                re[r] += __shfl_xor(re[r], m);
                rt[r] += __shfl_xor(rt[r], m);
            }
        }
        #pragma unroll
        for (int r = 0; r < 4; ++r) {
            if (s == r) {
                atomicAdd(&rsE[nb + r], re[r]);
                atomicAdd(&rsT[nb + r], rt[r]);
            }
        }
    }
    #pragma unroll
    for (int j = 0; j < 4; ++j) {
        colE[j] += __shfl_xor(colE[j], 16); colE[j] += __shfl_xor(colE[j], 32);
        colT[j] += __shfl_xor(colT[j], 16); colT[j] += __shfl_xor(colT[j], 32);
        if (q == 0) {
            atomicAdd(&csE[mcol[j]], colE[j]);
            atomicAdd(&csT[mcol[j]], colT[j]);
        }
    }
}

// ---- parallel finalize: 16 blocks, device-scope atomic accumulation; last
//      block (done counter) writes out. atomicAdd(p,0) read avoids stale L2. ----
__global__ __launch_bounds__(256) void finalize_kernel(
    const float* __restrict__ rsum_e, const float* __restrict__ rsum_t,
    const float* __restrict__ csum_e, const float* __restrict__ csum_t,
    const int* __restrict__ labels, const int* __restrict__ hist,
    const float* __restrict__ ent_partial,
    float* __restrict__ ce_acc, float* __restrict__ ent_acc,
    int* __restrict__ done, float* __restrict__ out) {
    __shared__ float red[4], red2[4];
    int b = blockIdx.x, tid = threadIdx.x;
    int n = b * 256 + tid;                 // covers 0..4095 exactly
    float Sn = (float)hist[labels[n]];
    float part = 0.0f;
    #pragma unroll
    for (int p = 0; p < 3; ++p) {
        part += Sn * (__logf(rsum_e[p * B_SZ + n]) - SHIFT) - rsum_t[p * B_SZ + n];
        part += Sn * (__logf(csum_e[p * B_SZ + n]) - SHIFT) - csum_t[p * B_SZ + n];
    }
    float ep = (b < 4) ? ent_partial[b * 256 + tid] : 0.0f;
    #pragma unroll
    for (int m = 1; m < 64; m <<= 1) {
        part += __shfl_xor(part, m);
        ep   += __shfl_xor(ep, m);
    }
    if ((tid & 63) == 0) { red[tid >> 6] = part; red2[tid >> 6] = ep; }
    __syncthreads();
    if (tid == 0) {
        atomicAdd(ce_acc, red[0] + red[1] + red[2] + red[3]);
        atomicAdd(ent_acc, red2[0] + red2[1] + red2[2] + red2[3]);
        __threadfence();
        if (atomicAdd(done, 1) == 15) {        // last of 16 blocks
            float ce = atomicAdd(ce_acc, 0.0f);    // coherent read
            float ent = atomicAdd(ent_acc, 0.0f);
            float contr = ce / (6.0f * (float)B_SZ);
            ent /= (float)B_SZ;
            out[0] = contr + 0.2f * ent;
            out[1] = contr;
            out[2] = ent;
        }
    }
}

// ---- workspace layout (bytes) ----
//   0       : fp8 feats (K-interleaved), 3*4096*512 = 6,291,456
//   6291456 : times[3][4096] f32   (49,152)
//   6340608 : rsum_e[12288 f]  \
//   6389760 : rsum_t           | zero region: 49155 floats
//   6438912 : csum_e           | (incl. ce_acc, ent_acc, done)
//   6488064 : csum_t           |
//   6537216 : ce_acc f32; 6537220: ent_acc f32; 6537224: done i32
//   6537228 : ent_partial[1024] f32 (every slot written by its dna block)
//   6541324 : hist[512] int (fully written by prep block 0)
extern "C" void kernel_launch(void* const* d_in, const int* in_sizes, int n_in,
                              void* d_out, int out_size, void* d_ws, size_t ws_size,
                              hipStream_t stream) {
    const float* img    = (const float*)d_in[0];
    const float* dna    = (const float*)d_in[1];
    const float* txt    = (const float*)d_in[2];
    const int*   labels = (const int*)d_in[3];
    const float* ls     = (const float*)d_in[4];
    const float* curv   = (const float*)d_in[5];

    char* ws = (char*)d_ws;
    u8*    f8     = (u8*)ws;
    float* times  = (float*)(ws + 6291456);
    float* rsum_e = (float*)(ws + 6340608);
    float* rsum_t = (float*)(ws + 6389760);
    float* csum_e = (float*)(ws + 6438912);
    float* csum_t = (float*)(ws + 6488064);
    float* ce_acc = (float*)(ws + 6537216);
    float* ent_acc= (float*)(ws + 6537220);
    int*   done   = (int*)  (ws + 6537224);
    float* ent_p  = (float*)(ws + 6537228);
    int*   hist   = (int*)  (ws + 6541324);

    prep_kernel<<<3072, 256, 0, stream>>>(img, dna, txt, curv, labels, hist,
                                          f8, times, rsum_e, ent_p);
    dim3 g(16, 16, 3);
    gemm_epi_kernel<<<g, 1024, 0, stream>>>(f8, times, labels, ls, curv,
                                            rsum_e, rsum_t, csum_e, csum_t);
    finalize_kernel<<<16, 256, 0, stream>>>(rsum_e, rsum_t, csum_e, csum_t,
                                            labels, hist, ent_p,
                                            ce_acc, ent_acc, done, (float*)d_out);
}

// Round 18
// 171.908 us; speedup vs baseline: 1.0897x; 1.0897x over previous
//
#include <hip/hip_runtime.h>
#include <stdint.h>

#define B_SZ 4096
#define D_SZ 512
#define SHIFT 64.0f

typedef __attribute__((ext_vector_type(4))) float floatx4;
typedef __attribute__((ext_vector_type(2))) long lng2;
typedef unsigned char u8;
typedef unsigned int u32;

#define GLD_LDS16(gp, sp)                                                              \
    __builtin_amdgcn_global_load_lds(                                                  \
        (const __attribute__((address_space(1))) void*)(gp),                           \
        (__attribute__((address_space(3))) void*)(sp), 16, 0, 0)

// ---- K1: fp32->fp8(e4m3) convert (K-interleaved layout) + per-row time,
//      fused: histogram (block 0), accumulator zeroing, entailment partials.
//      K-perm: within each 64B K-window, 8B group (h,c) -> slot c*2+h; applied
//      to BOTH operands => Grammian unchanged. ----
__global__ __launch_bounds__(256) void prep_kernel(
    const float* __restrict__ img, const float* __restrict__ dna,
    const float* __restrict__ txt, const float* __restrict__ curv_p,
    const int* __restrict__ labels, int* __restrict__ hist,
    u8* __restrict__ f8, float* __restrict__ times,
    float* __restrict__ zero_f, float* __restrict__ ent_partial) {
    __shared__ int lhist[512];
    __shared__ float red[4];
    int t = threadIdx.x;
    int gid = blockIdx.x * 256 + t;
    if (gid < 49155) zero_f[gid] = 0.0f;    // rsum/csum + ce_acc/ent_acc/done

    if (blockIdx.x == 0) {                  // label histogram, single block
        lhist[t] = 0; lhist[t + 256] = 0;
        __syncthreads();
        for (int n = t; n < B_SZ; n += 256) atomicAdd(&lhist[labels[n]], 1);
        __syncthreads();
        hist[t] = lhist[t]; hist[t + 256] = lhist[t + 256];
    }

    int wave = gid >> 6;  // 0..12287
    int lane = t & 63;
    const float* src = (wave < B_SZ) ? img : (wave < 2 * B_SZ) ? dna : txt;
    int row = wave & (B_SZ - 1);
    const float* p = src + row * D_SZ + lane * 8;
    float4 v0 = *(const float4*)(p);
    float4 v1 = *(const float4*)(p + 4);
    float ss = v0.x*v0.x + v0.y*v0.y + v0.z*v0.z + v0.w*v0.w
             + v1.x*v1.x + v1.y*v1.y + v1.z*v1.z + v1.w*v1.w;
    u32 w0 = __builtin_amdgcn_cvt_pk_fp8_f32(v0.x, v0.y, 0, false);
    w0 = __builtin_amdgcn_cvt_pk_fp8_f32(v0.z, v0.w, w0, true);
    u32 w1 = __builtin_amdgcn_cvt_pk_fp8_f32(v1.x, v1.y, 0, false);
    w1 = __builtin_amdgcn_cvt_pk_fp8_f32(v1.z, v1.w, w1, true);
    uint2 pk; pk.x = w0; pk.y = w1;
    // lane = 8B group: window lane>>3, half (lane>>2)&1, chunk lane&3
    int gperm = (lane & 56) | ((lane & 3) << 1) | ((lane >> 2) & 1);
    *(uint2*)(f8 + (size_t)wave * D_SZ + gperm * 8) = pk;

    bool isdna = (wave >= B_SZ) && (wave < 2 * B_SZ);
    float dot = 0.0f, ssy = 0.0f;
    if (isdna) {                            // matching image row for entailment
        const float* y = img + row * D_SZ + lane * 8;
        float4 y0 = *(const float4*)y, y1 = *(const float4*)(y + 4);
        dot = v0.x*y0.x + v0.y*y0.y + v0.z*y0.z + v0.w*y0.w
            + v1.x*y1.x + v1.y*y1.y + v1.z*y1.z + v1.w*y1.w;
        ssy = y0.x*y0.x + y0.y*y0.y + y0.z*y0.z + y0.w*y0.w
            + y1.x*y1.x + y1.y*y1.y + y1.z*y1.z + y1.w*y1.w;
    }
    #pragma unroll
    for (int m = 1; m < 64; m <<= 1) {
        ss += __shfl_xor(ss, m);
        if (isdna) { dot += __shfl_xor(dot, m); ssy += __shfl_xor(ssy, m); }
    }
    float curv = curv_p[0];
    float ep = 0.0f;
    if (lane == 0) {
        float xt = sqrtf(1.0f / curv + ss);
        times[wave] = xt;
        if (isdna) {
            float yt = sqrtf(1.0f / curv + ssy);
            float nx = sqrtf(ss);
            float c = curv * (dot - xt * yt);                      // <= -1
            float numer = yt + c * xt;
            float denom = nx * sqrtf(fmaxf(c * c - 1.0f, 0.0f));
            float ai = numer / (denom + 1e-8f);
            ai = fminf(fmaxf(ai, -1.0f + 1e-8f), 1.0f - 1e-8f);
            float ang = acosf(ai);
            float as_in = 0.2f / (nx * sqrtf(curv) + 1e-6f);       // 2*min_radius
            as_in = fminf(fmaxf(as_in, -1.0f + 1e-6f), 1.0f - 1e-6f);
            float ap = asinf(as_in);
            ep = fmaxf(ang - ap, 0.0f);
        }
    }
    if (blockIdx.x >= 1024 && blockIdx.x < 2048) {   // pure-dna blocks
        if (lane == 0) red[t >> 6] = ep;
        __syncthreads();
        if (t == 0) ent_partial[blockIdx.x - 1024] = red[0] + red[1] + red[2] + red[3];
    }
}

// ---- K2: batched fp8 MFMA GEMM (A·B^T), 256x128 tile, 512 threads = 8 waves,
//      64x64 patch/wave (R14 optimum, reproduced). K-interleaved fp8 => b128
//      frag reads with bijective swizzle slot = r*4+(q^((r>>1)&3)) (0
//      conflicts). LDS 56 KB (8 KB shaper pad in sB) -> 2 blocks/CU ->
//      128-VGPR budget; body 92 -> no spill. Staging 288 MB.
//      NOTE (R17): 1024-thread blocks are pinned to a 64-VGPR budget by the
//      allocator regardless of LDS/attributes -> always spill -> dead end.
//      NOTE (R15): per-block __threadfence() = L2-writeback storm (97->267us).
__global__ __launch_bounds__(512) void gemm_epi_kernel(
    const u8* __restrict__ f8, const float* __restrict__ times,
    const int* __restrict__ labels,
    const float* __restrict__ ls_p, const float* __restrict__ curv_p,
    float* __restrict__ rsum_e, float* __restrict__ rsum_t,
    float* __restrict__ csum_e, float* __restrict__ csum_t) {
    __shared__ u8 sA[2][256 * 64];    // 32 KB
    __shared__ u8 sB[2][12288];       // 24 KB; per buf only [0,8192) used,
                                      // [8192,12288) = occupancy-shaper pad

    int z = blockIdx.z;                   // 0:(img,dna) 1:(img,txt) 2:(dna,txt)
    int pa = (z == 2) ? 1 : 0;
    int pb = (z == 0) ? 1 : 2;
    const u8* A  = f8 + (size_t)pa * (B_SZ * D_SZ);
    const u8* Bm = f8 + (size_t)pb * (B_SZ * D_SZ);

    int t = threadIdx.x;
    int rowBlk = blockIdx.y * 256;
    int colBlk = blockIdx.x * 128;
    int wave = t >> 6, lane = t & 63;
    int rq  = wave >> 1;                  // row 64-group (0..3)
    int chh = wave & 1;                   // col 64-group (0..1)

    int lrow = lane >> 2;
    int lch  = (lane & 3) ^ ((lane >> 3) & 3);
    const u8* gA0 = A  + (size_t)(rowBlk + wave * 32 + lrow)      * D_SZ + lch * 16;
    const u8* gA1 = A  + (size_t)(rowBlk + wave * 32 + 16 + lrow) * D_SZ + lch * 16;
    const u8* gB  = Bm + (size_t)(colBlk + wave * 16 + lrow)      * D_SZ + lch * 16;

    int q = lane >> 4, s = lane & 15;

    floatx4 acc[4][4];
    #pragma unroll
    for (int ii = 0; ii < 4; ++ii)
        #pragma unroll
        for (int j = 0; j < 4; ++j) acc[ii][j] = (floatx4){0.f, 0.f, 0.f, 0.f};

    {   // prologue: stage super-iter 0 (K-bytes [0,64)) into buffer 0
        GLD_LDS16(gA0, &sA[0][wave * 2048]);
        GLD_LDS16(gA1, &sA[0][wave * 2048 + 1024]);
        GLD_LDS16(gB,  &sB[0][wave * 1024]);
    }

    for (int si = 0; si < D_SZ / 64; ++si) {
        int cur = si & 1;
        __syncthreads();   // buf[cur] landed; prior frag reads done
        if (si < D_SZ / 64 - 1) {
            int ko = (si + 1) * 64;
            int nxt = cur ^ 1;
            GLD_LDS16(gA0 + ko, &sA[nxt][wave * 2048]);
            GLD_LDS16(gA1 + ko, &sA[nxt][wave * 2048 + 1024]);
            GLD_LDS16(gB  + ko, &sB[nxt][wave * 1024]);
        }
        lng2 afp[4], bfp[4];
        #pragma unroll
        for (int ii = 0; ii < 4; ++ii) {
            int r = rq * 64 + ii * 16 + s;
            afp[ii] = *(const lng2*)&sA[cur][r * 64 + ((q ^ ((r >> 1) & 3)) << 4)];
        }
        #pragma unroll
        for (int j = 0; j < 4; ++j) {
            int r = chh * 64 + j * 16 + s;
            bfp[j] = *(const lng2*)&sB[cur][r * 64 + ((q ^ ((r >> 1) & 3)) << 4)];
        }
        #pragma unroll
        for (int ii = 0; ii < 4; ++ii)
            #pragma unroll
            for (int j = 0; j < 4; ++j) {
                acc[ii][j] = __builtin_amdgcn_mfma_f32_16x16x32_fp8_fp8(
                    afp[ii].x, bfp[j].x, acc[ii][j], 0, 0, 0);
                acc[ii][j] = __builtin_amdgcn_mfma_f32_16x16x32_fp8_fp8(
                    afp[ii].y, bfp[j].y, acc[ii][j], 0, 0, 0);
            }
    }

    // ---- slim fused epilogue (verified R7-R17) ----
    float ls = ls_p[0];
    float curv = curv_p[0];
    float rsc = rsqrtf(curv);
    float c2 = -ls * rsc;
    float c1 = c2 * 0.69314718f;
    float sh2p = SHIFT * 1.44269504f + c2;
    const float* tA = times + pa * B_SZ;
    const float* tB = times + pb * B_SZ;

    int rowbase = rowBlk + rq * 64;
    int colbase = colBlk + chh * 64;

    float tb[4]; int lb[4]; int mcol[4];
    #pragma unroll
    for (int j = 0; j < 4; ++j) {
        mcol[j] = colbase + j * 16 + s;
        tb[j] = tB[mcol[j]];
        lb[j] = labels[mcol[j]];
    }
    float colE[4] = {0.f, 0.f, 0.f, 0.f}, colT[4] = {0.f, 0.f, 0.f, 0.f};

    float* rsE = rsum_e + z * B_SZ;
    float* rsT = rsum_t + z * B_SZ;
    float* csE = csum_e + z * B_SZ;
    float* csT = csum_t + z * B_SZ;

    #pragma unroll
    for (int ii = 0; ii < 4; ++ii) {
        int nb = rowbase + ii * 16 + q * 4;   // this lane's 4 C rows
        float cta[4]; int la[4];
        #pragma unroll
        for (int r = 0; r < 4; ++r) { cta[r] = curv * tA[nb + r]; la[r] = labels[nb + r]; }
        float re[4] = {0.f, 0.f, 0.f, 0.f}, rt[4] = {0.f, 0.f, 0.f, 0.f};
        #pragma unroll
        for (int j = 0; j < 4; ++j) {
            floatx4 a = acc[ii][j];
            #pragma unroll
            for (int r = 0; r < 4; ++r) {
                float zc = fmaf(-curv, a[r], cta[r] * tb[j]);
                zc = fmaxf(zc, 1.0f + 1e-8f);
                float lz = __log2f(zc);
                float e = __builtin_amdgcn_exp2f(fmaf(c2, lz, sh2p));
                float tl = (la[r] == lb[j]) ? fmaf(c1, lz, c1) : 0.0f;
                re[r] += e; rt[r] += tl;
                colE[j] += e; colT[j] += tl;
            }
        }
        #pragma unroll
        for (int r = 0; r < 4; ++r) {
            #pragma unroll
            for (int m = 1; m <= 8; m <<= 1) {
                re[r] += __shfl_xor(re[r], m);
                rt[r] += __shfl_xor(rt[r], m);
            }
        }
        #pragma unroll
        for (int r = 0; r < 4; ++r) {
            if (s == r) {
                atomicAdd(&rsE[nb + r], re[r]);
                atomicAdd(&rsT[nb + r], rt[r]);
            }
        }
    }
    #pragma unroll
    for (int j = 0; j < 4; ++j) {
        colE[j] += __shfl_xor(colE[j], 16); colE[j] += __shfl_xor(colE[j], 32);
        colT[j] += __shfl_xor(colT[j], 16); colT[j] += __shfl_xor(colT[j], 32);
        if (q == 0) {
            atomicAdd(&csE[mcol[j]], colE[j]);
            atomicAdd(&csT[mcol[j]], colT[j]);
        }
    }
}

// ---- parallel finalize: 16 blocks, device-scope atomic accumulation; last
//      block (done counter) writes out. atomicAdd(p,0) read avoids stale L2. ----
__global__ __launch_bounds__(256) void finalize_kernel(
    const float* __restrict__ rsum_e, const float* __restrict__ rsum_t,
    const float* __restrict__ csum_e, const float* __restrict__ csum_t,
    const int* __restrict__ labels, const int* __restrict__ hist,
    const float* __restrict__ ent_partial,
    float* __restrict__ ce_acc, float* __restrict__ ent_acc,
    int* __restrict__ done, float* __restrict__ out) {
    __shared__ float red[4], red2[4];
    int b = blockIdx.x, tid = threadIdx.x;
    int n = b * 256 + tid;                 // covers 0..4095 exactly
    float Sn = (float)hist[labels[n]];
    float part = 0.0f;
    #pragma unroll
    for (int p = 0; p < 3; ++p) {
        part += Sn * (__logf(rsum_e[p * B_SZ + n]) - SHIFT) - rsum_t[p * B_SZ + n];
        part += Sn * (__logf(csum_e[p * B_SZ + n]) - SHIFT) - csum_t[p * B_SZ + n];
    }
    float ep = (b < 4) ? ent_partial[b * 256 + tid] : 0.0f;
    #pragma unroll
    for (int m = 1; m < 64; m <<= 1) {
        part += __shfl_xor(part, m);
        ep   += __shfl_xor(ep, m);
    }
    if ((tid & 63) == 0) { red[tid >> 6] = part; red2[tid >> 6] = ep; }
    __syncthreads();
    if (tid == 0) {
        atomicAdd(ce_acc, red[0] + red[1] + red[2] + red[3]);
        atomicAdd(ent_acc, red2[0] + red2[1] + red2[2] + red2[3]);
        __threadfence();
        if (atomicAdd(done, 1) == 15) {        // last of 16 blocks
            float ce = atomicAdd(ce_acc, 0.0f);    // coherent read
            float ent = atomicAdd(ent_acc, 0.0f);
            float contr = ce / (6.0f * (float)B_SZ);
            ent /= (float)B_SZ;
            out[0] = contr + 0.2f * ent;
            out[1] = contr;
            out[2] = ent;
        }
    }
}

// ---- workspace layout (bytes) ----
//   0       : fp8 feats (K-interleaved), 3*4096*512 = 6,291,456
//   6291456 : times[3][4096] f32   (49,152)
//   6340608 : rsum_e[12288 f]  \
//   6389760 : rsum_t           | zero region: 49155 floats
//   6438912 : csum_e           | (incl. ce_acc, ent_acc, done)
//   6488064 : csum_t           |
//   6537216 : ce_acc f32; 6537220: ent_acc f32; 6537224: done i32
//   6537228 : ent_partial[1024] f32 (every slot written by its dna block)
//   6541324 : hist[512] int (fully written by prep block 0)
extern "C" void kernel_launch(void* const* d_in, const int* in_sizes, int n_in,
                              void* d_out, int out_size, void* d_ws, size_t ws_size,
                              hipStream_t stream) {
    const float* img    = (const float*)d_in[0];
    const float* dna    = (const float*)d_in[1];
    const float* txt    = (const float*)d_in[2];
    const int*   labels = (const int*)d_in[3];
    const float* ls     = (const float*)d_in[4];
    const float* curv   = (const float*)d_in[5];

    char* ws = (char*)d_ws;
    u8*    f8     = (u8*)ws;
    float* times  = (float*)(ws + 6291456);
    float* rsum_e = (float*)(ws + 6340608);
    float* rsum_t = (float*)(ws + 6389760);
    float* csum_e = (float*)(ws + 6438912);
    float* csum_t = (float*)(ws + 6488064);
    float* ce_acc = (float*)(ws + 6537216);
    float* ent_acc= (float*)(ws + 6537220);
    int*   done   = (int*)  (ws + 6537224);
    float* ent_p  = (float*)(ws + 6537228);
    int*   hist   = (int*)  (ws + 6541324);

    prep_kernel<<<3072, 256, 0, stream>>>(img, dna, txt, curv, labels, hist,
                                          f8, times, rsum_e, ent_p);
    dim3 g(32, 16, 3);
    gemm_epi_kernel<<<g, 512, 0, stream>>>(f8, times, labels, ls, curv,
                                           rsum_e, rsum_t, csum_e, csum_t);
    finalize_kernel<<<16, 256, 0, stream>>>(rsum_e, rsum_t, csum_e, csum_t,
                                            labels, hist, ent_p,
                                            ce_acc, ent_acc, done, (float*)d_out);
}